// Round 1
// baseline (4275.996 us; speedup 1.0000x reference)
//
#include <hip/hip_runtime.h>

#define BATCH 128
#define SEQ   512
#define EMB   512
#define HID   1024
#define NCLS  1000
#define NBLK  128    // 8 row groups x 16 blocks
#define TPB   512    // 8 waves; split-K: wave w owns hi K-steps {w+8m}, lo {w+8mm}

using short8 = __attribute__((ext_vector_type(8))) short;
using f32x4  = __attribute__((ext_vector_type(4))) float;
typedef unsigned long long u64;

__device__ __forceinline__ short f2bf(float f) {
    unsigned u = __float_as_uint(f);
    unsigned r = (u + 0x7fffu + ((u >> 16) & 1u)) >> 16;   // RNE
    return (short)r;
}
__device__ __forceinline__ float bf2f(short s) {
    unsigned u = ((unsigned)(unsigned short)s) << 16;
    return __uint_as_float(u);
}
__device__ __forceinline__ short8 pack8(float4 a, float4 b) {
    short8 s;
    s[0] = f2bf(a.x); s[1] = f2bf(a.y); s[2] = f2bf(a.z); s[3] = f2bf(a.w);
    s[4] = f2bf(b.x); s[5] = f2bf(b.y); s[6] = f2bf(b.z); s[7] = f2bf(b.w);
    return s;
}
__device__ __forceinline__ short8 mk8(u64 lo, u64 hi) {
    union { u64 d[2]; short8 s; } u;
    u.d[0] = lo; u.d[1] = hi;
    return u.s;
}

// ---- ws layout (bytes) ---- unchanged from previous version
#define OFF_CH0 0u
#define OFF_CL0 262144u
#define OFF_BAR 524288u          // 8 counters, 256B apart
#define OFF_CH1 526336u
#define OFF_CL1 788480u
#define OFF_H   1050624u
#define ZERO_I4 32896u           // first 526336 bytes zeroed as int4

__global__ void mgu_init(int4* __restrict__ ws4) {
    unsigned i = blockIdx.x * blockDim.x + threadIdx.x;
    if (i < ZERO_I4) ws4[i] = make_int4(0, 0, 0, 0);
}

// ---------------- sequential scan, split-K over waves ----------------
// Block b: rows r0=(b>>4)*16, h-cols jb=(b&15)*64. Wave w: K-slice
// hi ks in {w+8m, m=0..5} (m=0,1 -> emb, m=2..5 -> h), lo le in {w+8mm}.
// A-frags load DIRECTLY to registers (emb: cached loads; h: relaxed AGENT
// atomics = LLC-coherent bypass). B resident in 48 short8 (192 VGPRs); lo-B
// reuses Bf[c*6+2+mm] exactly (k-row 512+32*(w+8mm) == 32*(w+8*(mm+2))).
// Cross-wave reduction of f32x4 partials via 64KB LDS, lane-contiguous b128
// (conflict-free). Barrier/exchange mechanics identical to prior version.
__global__ __launch_bounds__(TPB, 1) void mgu_scan(
    const int* __restrict__ x, const float* __restrict__ emb,
    const float* __restrict__ Wz, const float* __restrict__ bz,
    const float* __restrict__ Wh, const float* __restrict__ bh,
    short* __restrict__ ch0, short* __restrict__ cl0,
    short* __restrict__ ch1, short* __restrict__ cl1,
    unsigned* __restrict__ bars, float* __restrict__ h)
{
    __shared__ f32x4 Rbuf[8][8][64];   // [src wave][col group][lane] = 64 KiB

    const int tid  = threadIdx.x;
    const int w    = tid >> 6;               // wave 0..7 = K-slice
    const int lane = tid & 63;
    const int q    = lane >> 4;              // quad 0..3
    const int n    = lane & 15;              // MFMA col / A-row index
    const int blk  = blockIdx.x;
    const int r0   = (blk >> 4) << 4;        // row-group base
    const int jb   = (blk & 15) << 6;        // block h-col base (64 cols)
    const int j0   = jb + (w << 3);          // this wave's output cols j0..j0+7
    unsigned* bar  = bars + ((blk >> 4) << 6);

    // ---- persistent B fragments: Bf[c*6+m] = W[32*(w+8m)+q*8+i][jb+8c+(n&7)] ----
    const float* Wg = (n < 8) ? Wz : Wh;
    short8 Bf[48];
#pragma unroll
    for (int c = 0; c < 8; ++c) {
#pragma unroll
        for (int m = 0; m < 6; ++m) {
            const float* wp = Wg + jb + (c << 3) + (n & 7);
            short8 f;
#pragma unroll
            for (int i = 0; i < 8; ++i)
                f[i] = f2bf(wp[(long)((w + 8 * m) * 32 + q * 8 + i) * HID]);
            Bf[c * 6 + m] = f;
        }
    }
    const float bzv = bz[j0 + (n & 7)];
    const float bhv = bh[j0 + (n & 7)];

    float hreg[4] = {0.f, 0.f, 0.f, 0.f};    // lanes n<8: h, rows r0+q*4+r2, col j0+n

    const int xrow = (r0 + n) * SEQ;                         // token stream for A-row n
    const int hoff = (r0 + n) * HID + (w << 5) + (q << 3);   // h frag base (shorts), +256*mm
    const int eoff = (w << 5) + (q << 3);                    // emb frag base (floats), +256*m

    // prefetch emb fragments for t=0
    short8 fe0, fe1;
    {
        int tok = x[xrow];
        const float* ep = emb + (long)tok * EMB + eoff;
        float4 a0 = *(const float4*)(ep);
        float4 a1 = *(const float4*)(ep + 4);
        float4 b0 = *(const float4*)(ep + 256);
        float4 b1 = *(const float4*)(ep + 260);
        fe0 = pack8(a0, a1);
        fe1 = pack8(b0, b1);
    }

    for (int t = 0; t < SEQ; ++t) {
        const short* chR = (t & 1) ? ch1 : ch0;
        const short* clR = (t & 1) ? cl1 : cl0;
        short*       chW = (t & 1) ? ch0 : ch1;
        short*       clW = (t & 1) ? cl0 : cl1;

        // next token early (ready by barrier time; independent of everything)
        int tok_nxt = x[xrow + ((t < SEQ - 1) ? t + 1 : t)];

        // ---- issue h hi/lo fragment loads (LLC-coherent, straight to regs) ----
        u64 hh[8], ll[8];
#pragma unroll
        for (int mm = 0; mm < 4; ++mm) {
            const u64* hp = (const u64*)(chR + hoff + (mm << 8));
            hh[2 * mm]     = __hip_atomic_load(hp,     __ATOMIC_RELAXED, __HIP_MEMORY_SCOPE_AGENT);
            hh[2 * mm + 1] = __hip_atomic_load(hp + 1, __ATOMIC_RELAXED, __HIP_MEMORY_SCOPE_AGENT);
        }
#pragma unroll
        for (int mm = 0; mm < 4; ++mm) {
            const u64* lp = (const u64*)(clR + hoff + (mm << 8));
            ll[2 * mm]     = __hip_atomic_load(lp,     __ATOMIC_RELAXED, __HIP_MEMORY_SCOPE_AGENT);
            ll[2 * mm + 1] = __hip_atomic_load(lp + 1, __ATOMIC_RELAXED, __HIP_MEMORY_SCOPE_AGENT);
        }

        f32x4 acc[8];
#pragma unroll
        for (int c = 0; c < 8; ++c) acc[c] = (f32x4){0.f, 0.f, 0.f, 0.f};

        // ---- emb MFMAs first: frags already in regs, hides h-load latency ----
#pragma unroll
        for (int c = 0; c < 8; ++c)
            acc[c] = __builtin_amdgcn_mfma_f32_16x16x32_bf16(fe0, Bf[c * 6 + 0], acc[c], 0, 0, 0);
#pragma unroll
        for (int c = 0; c < 8; ++c)
            acc[c] = __builtin_amdgcn_mfma_f32_16x16x32_bf16(fe1, Bf[c * 6 + 1], acc[c], 0, 0, 0);

        // ---- h hi, then lo correction (same B frags, same offsets) ----
#pragma unroll
        for (int mm = 0; mm < 4; ++mm) {
            short8 fh = mk8(hh[2 * mm], hh[2 * mm + 1]);
#pragma unroll
            for (int c = 0; c < 8; ++c)
                acc[c] = __builtin_amdgcn_mfma_f32_16x16x32_bf16(fh, Bf[c * 6 + 2 + mm], acc[c], 0, 0, 0);
        }
#pragma unroll
        for (int mm = 0; mm < 4; ++mm) {
            short8 fl = mk8(ll[2 * mm], ll[2 * mm + 1]);
#pragma unroll
            for (int c = 0; c < 8; ++c)
                acc[c] = __builtin_amdgcn_mfma_f32_16x16x32_bf16(fl, Bf[c * 6 + 2 + mm], acc[c], 0, 0, 0);
        }

        // ---- cross-wave reduction: lane-contiguous b128, conflict-free ----
#pragma unroll
        for (int c = 0; c < 8; ++c) Rbuf[w][c][lane] = acc[c];
        __syncthreads();
        f32x4 r = Rbuf[0][w][lane];
#pragma unroll
        for (int w2 = 1; w2 < 8; ++w2) r += Rbuf[w2][w][lane];

        // z-pre in lanes n<8, h~-pre in n>=8 (same col); partner = lane^8
        float oarr[4];
        oarr[0] = __shfl_xor(r[0], 8, 64);
        oarr[1] = __shfl_xor(r[1], 8, 64);
        oarr[2] = __shfl_xor(r[2], 8, 64);
        oarr[3] = __shfl_xor(r[3], 8, 64);

        if (n < 8) {
            const int j = j0 + n;
#pragma unroll
            for (int r2 = 0; r2 < 4; ++r2) {
                float z  = 1.f / (1.f + __expf(-(r[r2] + bzv)));
                float ht = tanhf(oarr[r2] + bhv);
                float ho = hreg[r2];
                float hn = ho + z * (ht - ho);
                hreg[r2] = hn;
                int rr = (r0 + q * 4 + r2) * HID + j;
                if (t < SEQ - 1) {
                    short hi = f2bf(hn);
                    __hip_atomic_store(chW + rr, hi, __ATOMIC_RELAXED, __HIP_MEMORY_SCOPE_AGENT);
                    __hip_atomic_store(clW + rr, f2bf(hn - bf2f(hi)), __ATOMIC_RELAXED, __HIP_MEMORY_SCOPE_AGENT);
                } else {
                    h[rr] = hn;          // final state, normal store (kernel-boundary flush)
                }
            }
        }

        if (t < SEQ - 1) {
            // release: __syncthreads drains vmcnt(0) (bypass stores visible at LLC)
            __syncthreads();
            if (tid == 0)
                __hip_atomic_fetch_add(bar, 1u, __ATOMIC_RELAXED, __HIP_MEMORY_SCOPE_AGENT);
            // prefetch next emb fragments into regs; overlaps barrier round-trip
            {
                const float* ep = emb + (long)tok_nxt * EMB + eoff;
                float4 a0 = *(const float4*)(ep);
                float4 a1 = *(const float4*)(ep + 4);
                float4 b0 = *(const float4*)(ep + 256);
                float4 b1 = *(const float4*)(ep + 260);
                fe0 = pack8(a0, a1);
                fe1 = pack8(b0, b1);
            }
            if (tid == 0) {
                unsigned tgt = (unsigned)(t + 1) * 16u;
                while (__hip_atomic_load(bar, __ATOMIC_RELAXED, __HIP_MEMORY_SCOPE_AGENT) < tgt)
                    __builtin_amdgcn_s_sleep(1);
            }
            __syncthreads();
        }
    }
}

// ---------------- final FC: logits = h @ Wfc + bfc, full fp32 ----------------
__global__ __launch_bounds__(256) void mgu_fc(const float* __restrict__ h,
                                              const float* __restrict__ Wfc,
                                              const float* __restrict__ bfc,
                                              float* __restrict__ out) {
    __shared__ float hs[BATCH][65];
    const int tid = threadIdx.x;
    const int n0  = blockIdx.x * 8;
    const int b   = tid & 127;
    const int nn  = tid >> 7;
    const int nc  = n0 + nn * 4;
    float acc0 = 0.f, acc1 = 0.f, acc2 = 0.f, acc3 = 0.f;

    for (int k0 = 0; k0 < HID; k0 += 64) {
        __syncthreads();
#pragma unroll
        for (int jj = 0; jj < 8; ++jj) {
            int idx = tid + jj * 256;
            int bb  = idx >> 4;
            int kk  = (idx & 15) << 2;
            const float4 v = *(const float4*)(h + bb * HID + k0 + kk);
            hs[bb][kk] = v.x; hs[bb][kk + 1] = v.y; hs[bb][kk + 2] = v.z; hs[bb][kk + 3] = v.w;
        }
        __syncthreads();
#pragma unroll 8
        for (int k = 0; k < 64; ++k) {
            float hv = hs[b][k];
            const float4 wv = *(const float4*)(Wfc + (long)(k0 + k) * NCLS + nc);
            acc0 += hv * wv.x; acc1 += hv * wv.y; acc2 += hv * wv.z; acc3 += hv * wv.w;
        }
    }
    float* op = out + b * NCLS + nc;
    op[0] = acc0 + bfc[nc + 0];
    op[1] = acc1 + bfc[nc + 1];
    op[2] = acc2 + bfc[nc + 2];
    op[3] = acc3 + bfc[nc + 3];
}

extern "C" void kernel_launch(void* const* d_in, const int* in_sizes, int n_in,
                              void* d_out, int out_size, void* d_ws, size_t ws_size,
                              hipStream_t stream) {
    const int*   x   = (const int*)  d_in[0];
    const float* emb = (const float*)d_in[1];
    const float* Wz  = (const float*)d_in[2];
    const float* bz  = (const float*)d_in[3];
    const float* Wh  = (const float*)d_in[4];
    const float* bh  = (const float*)d_in[5];
    const float* Wfc = (const float*)d_in[6];
    const float* bfc = (const float*)d_in[7];
    float* out = (float*)d_out;

    char* ws = (char*)d_ws;
    short*    ch0  = (short*)   (ws + OFF_CH0);
    short*    cl0  = (short*)   (ws + OFF_CL0);
    unsigned* bars = (unsigned*)(ws + OFF_BAR);
    short*    ch1  = (short*)   (ws + OFF_CH1);
    short*    cl1  = (short*)   (ws + OFF_CL1);
    float*    h    = (float*)   (ws + OFF_H);

    mgu_init<<<129, 256, 0, stream>>>((int4*)ws);   // zero ch0/cl0/bars

    mgu_scan<<<NBLK, TPB, 0, stream>>>(x, emb, Wz, bz, Wh, bh,
                                       ch0, cl0, ch1, cl1, bars, h);

    mgu_fc<<<125, 256, 0, stream>>>(h, Wfc, bfc, out);
}

// Round 3
// 3521.341 us; speedup vs baseline: 1.2143x; 1.2143x over previous
//
#include <hip/hip_runtime.h>

#define BATCH 128
#define SEQ   512
#define EMB   512
#define HID   1024
#define NCLS  1000
#define NBLK  128    // 8 row groups x 16 blocks
#define TPB   512    // 8 waves; split-K: wave w owns hi K-steps {w+8m}, lo {w+8mm}

using short8 = __attribute__((ext_vector_type(8))) short;
using f32x4  = __attribute__((ext_vector_type(4))) float;
typedef unsigned long long u64;

__device__ __forceinline__ short f2bf(float f) {
    unsigned u = __float_as_uint(f);
    unsigned r = (u + 0x7fffu + ((u >> 16) & 1u)) >> 16;   // RNE
    return (short)r;
}
__device__ __forceinline__ float bf2f(short s) {
    unsigned u = ((unsigned)(unsigned short)s) << 16;
    return __uint_as_float(u);
}
__device__ __forceinline__ short8 pack8(float4 a, float4 b) {
    short8 s;
    s[0] = f2bf(a.x); s[1] = f2bf(a.y); s[2] = f2bf(a.z); s[3] = f2bf(a.w);
    s[4] = f2bf(b.x); s[5] = f2bf(b.y); s[6] = f2bf(b.z); s[7] = f2bf(b.w);
    return s;
}
__device__ __forceinline__ short8 mk8(u64 lo, u64 hi) {
    union { u64 d[2]; short8 s; } u;
    u.d[0] = lo; u.d[1] = hi;
    return u.s;
}

// ---- ws layout (bytes) ----
// Exchange buffers hold h in MFMA-FRAGMENT layout:
//   frag(rg, ks', plane, lane, i): short off = rg*16384 + ks'*512 + plane*256 + lane*4 + i
//   rg = rowgroup 0..7, ks' = h K-step 0..31 (h-cols 32ks'..+31), plane = i-half,
//   lane = 16*q + row, i = k low 2 bits. Plane stride = 256 shorts = 64 u64.
#define OFF_CH0 0u
#define OFF_CL0 262144u
#define OFF_BAR 524288u          // 8 counters, 256B apart
#define OFF_CH1 526336u
#define OFF_CL1 788480u
#define OFF_H   1050624u
#define ZERO_I4 32896u           // first 526336 bytes zeroed as int4

__global__ void mgu_init(int4* __restrict__ ws4) {
    unsigned i = blockIdx.x * blockDim.x + threadIdx.x;
    if (i < ZERO_I4) ws4[i] = make_int4(0, 0, 0, 0);
}

// ---------------- sequential scan, split-K over waves, fragment-layout exchange ----------------
// Block b: rows r0=(b>>4)*16, h-cols jb=(b&15)*64. Wave w: K-slice hi ks in {w+8m}
// (m=0,1 emb / m=2..5 h), lo le in {w+8mm}. A-frags load straight to registers:
//   emb: cached per-lane gathers;  h: coalesced 512B agent-atomic u64 loads from
//   fragment-layout LLC buffers (each fragment loaded exactly once per block).
// Writer side: in-wave 16x8 LDS transpose -> 2 coalesced u64 stores (lanes<32).
// B resident in 48 short8 (192 VGPRs); lo-B reuses Bf[c*6+2+mm] (k-row identity).
// Cross-wave reduction via 64KB LDS, lane-contiguous b128 (conflict-free).
__global__ __launch_bounds__(TPB, 1) void mgu_scan(
    const int* __restrict__ x, const float* __restrict__ emb,
    const float* __restrict__ Wz, const float* __restrict__ bz,
    const float* __restrict__ Wh, const float* __restrict__ bh,
    short* __restrict__ ch0, short* __restrict__ cl0,
    short* __restrict__ ch1, short* __restrict__ cl1,
    unsigned* __restrict__ bars, float* __restrict__ h)
{
    __shared__ f32x4 Rbuf[8][8][64];   // [src wave][col group][lane] = 64 KiB
    __shared__ short TrH[8][16][8];    // [wave][row][col] transpose scratch (2KB)
    __shared__ short TrL[8][16][8];    // lo part (2KB)

    const int tid  = threadIdx.x;
    const int w    = tid >> 6;               // wave 0..7 = K-slice
    const int lane = tid & 63;
    const int q    = lane >> 4;              // quad 0..3
    const int n    = lane & 15;              // MFMA col / A-row index
    const int blk  = blockIdx.x;
    const int r0   = (blk >> 4) << 4;        // row-group base
    const int jb   = (blk & 15) << 6;        // block h-col base (64 cols)
    const int j0   = jb + (w << 3);          // this wave's output cols j0..j0+7
    const int frg  = (blk >> 4) * 16384;     // rowgroup base in exchange buffers (shorts)
    const int ksw  = ((blk & 15) << 1) + (w >> 2);   // fragment this wave writes
    const int qw   = w & 3;                          // quadrant within that fragment
    unsigned* bar  = bars + ((blk >> 4) << 6);

    // ---- persistent B fragments: Bf[c*6+m] = W[32*(w+8m)+q*8+i][jb+8c+(n&7)] ----
    const float* Wg = (n < 8) ? Wz : Wh;
    short8 Bf[48];
#pragma unroll
    for (int c = 0; c < 8; ++c) {
#pragma unroll
        for (int m = 0; m < 6; ++m) {
            const float* wp = Wg + jb + (c << 3) + (n & 7);
            short8 f;
#pragma unroll
            for (int i = 0; i < 8; ++i)
                f[i] = f2bf(wp[(long)((w + 8 * m) * 32 + q * 8 + i) * HID]);
            Bf[c * 6 + m] = f;
        }
    }
    const float bzv = bz[j0 + (n & 7)];
    const float bhv = bh[j0 + (n & 7)];

    float hreg[4] = {0.f, 0.f, 0.f, 0.f};    // lanes n<8: h, rows r0+q*4+r2, col j0+n

    const int xrow = (r0 + n) * SEQ;         // token stream for A-row n
    const int eoff = (w << 5) + (q << 3);    // emb frag base (floats), +256*m

    // prefetch emb fragments for t=0
    short8 fe0, fe1;
    {
        int tok = x[xrow];
        const float* ep = emb + (long)tok * EMB + eoff;
        float4 a0 = *(const float4*)(ep);
        float4 a1 = *(const float4*)(ep + 4);
        float4 b0 = *(const float4*)(ep + 256);
        float4 b1 = *(const float4*)(ep + 260);
        fe0 = pack8(a0, a1);
        fe1 = pack8(b0, b1);
    }

    for (int t = 0; t < SEQ; ++t) {
        const short* chR = (t & 1) ? ch1 : ch0;
        const short* clR = (t & 1) ? cl1 : cl0;
        short*       chW = (t & 1) ? ch0 : ch1;
        short*       clW = (t & 1) ? cl0 : cl1;

        // next token early (independent; ready by barrier time)
        int tok_nxt = x[xrow + ((t < SEQ - 1) ? t + 1 : t)];

        // ---- h hi/lo fragment loads: coalesced 512B planes, straight to regs ----
        // plane 0 at +0, plane 1 at +256 shorts = +64 u64 (NOT +32: that was R2's bug)
        u64 hh[8], ll[8];
#pragma unroll
        for (int mm = 0; mm < 4; ++mm) {
            const u64* hp = (const u64*)(chR + frg + (w + 8 * mm) * 512 + (lane << 2));
            hh[2 * mm]     = __hip_atomic_load(hp,      __ATOMIC_RELAXED, __HIP_MEMORY_SCOPE_AGENT);
            hh[2 * mm + 1] = __hip_atomic_load(hp + 64, __ATOMIC_RELAXED, __HIP_MEMORY_SCOPE_AGENT);
        }
#pragma unroll
        for (int mm = 0; mm < 4; ++mm) {
            const u64* lp = (const u64*)(clR + frg + (w + 8 * mm) * 512 + (lane << 2));
            ll[2 * mm]     = __hip_atomic_load(lp,      __ATOMIC_RELAXED, __HIP_MEMORY_SCOPE_AGENT);
            ll[2 * mm + 1] = __hip_atomic_load(lp + 64, __ATOMIC_RELAXED, __HIP_MEMORY_SCOPE_AGENT);
        }

        f32x4 acc[8];
#pragma unroll
        for (int c = 0; c < 8; ++c) acc[c] = (f32x4){0.f, 0.f, 0.f, 0.f};

        // ---- emb MFMAs first: frags already in regs, hide h-load latency ----
#pragma unroll
        for (int c = 0; c < 8; ++c)
            acc[c] = __builtin_amdgcn_mfma_f32_16x16x32_bf16(fe0, Bf[c * 6 + 0], acc[c], 0, 0, 0);
#pragma unroll
        for (int c = 0; c < 8; ++c)
            acc[c] = __builtin_amdgcn_mfma_f32_16x16x32_bf16(fe1, Bf[c * 6 + 1], acc[c], 0, 0, 0);

        // ---- h hi, then lo correction (same B frags) ----
#pragma unroll
        for (int mm = 0; mm < 4; ++mm) {
            short8 fh = mk8(hh[2 * mm], hh[2 * mm + 1]);
#pragma unroll
            for (int c = 0; c < 8; ++c)
                acc[c] = __builtin_amdgcn_mfma_f32_16x16x32_bf16(fh, Bf[c * 6 + 2 + mm], acc[c], 0, 0, 0);
        }
#pragma unroll
        for (int mm = 0; mm < 4; ++mm) {
            short8 fl = mk8(ll[2 * mm], ll[2 * mm + 1]);
#pragma unroll
            for (int c = 0; c < 8; ++c)
                acc[c] = __builtin_amdgcn_mfma_f32_16x16x32_bf16(fl, Bf[c * 6 + 2 + mm], acc[c], 0, 0, 0);
        }

        // ---- cross-wave reduction: lane-contiguous b128, conflict-free ----
#pragma unroll
        for (int c = 0; c < 8; ++c) Rbuf[w][c][lane] = acc[c];
        __syncthreads();
        f32x4 r = Rbuf[0][w][lane];
#pragma unroll
        for (int w2 = 1; w2 < 8; ++w2) r += Rbuf[w2][w][lane];

        // z-pre in lanes n<8, h~-pre in n>=8 (same col); partner = lane^8
        float oarr[4];
        oarr[0] = __shfl_xor(r[0], 8, 64);
        oarr[1] = __shfl_xor(r[1], 8, 64);
        oarr[2] = __shfl_xor(r[2], 8, 64);
        oarr[3] = __shfl_xor(r[3], 8, 64);

        if (n < 8) {
            const int j = j0 + n;
#pragma unroll
            for (int r2 = 0; r2 < 4; ++r2) {
                float z  = 1.f / (1.f + __expf(-(r[r2] + bzv)));
                float ht = tanhf(oarr[r2] + bhv);
                float ho = hreg[r2];
                float hn = ho + z * (ht - ho);
                hreg[r2] = hn;
                if (t < SEQ - 1) {
                    short hi = f2bf(hn);
                    TrH[w][q * 4 + r2][n] = hi;
                    TrL[w][q * 4 + r2][n] = f2bf(hn - bf2f(hi));
                } else {
                    h[(r0 + q * 4 + r2) * HID + j] = hn;   // final state
                }
            }
        }

        if (t < SEQ - 1) {
            __syncthreads();   // transpose scratch visible
            // ---- coalesced fragment store: lanes<32, 2 x 128B segments/wave ----
            if (lane < 32) {
                const int p = lane >> 4, rr = lane & 15;
                u64 vh = *(const u64*)&TrH[w][rr][p << 2];
                u64 vl = *(const u64*)&TrL[w][rr][p << 2];
                const int off = frg + ksw * 512 + (p << 8) + (((qw << 4) + rr) << 2);
                __hip_atomic_store((u64*)(chW + off), vh, __ATOMIC_RELAXED, __HIP_MEMORY_SCOPE_AGENT);
                __hip_atomic_store((u64*)(clW + off), vl, __ATOMIC_RELAXED, __HIP_MEMORY_SCOPE_AGENT);
            }
            // release: __syncthreads drains vmcnt(0) (bypass stores visible at LLC)
            __syncthreads();
            if (tid == 0)
                __hip_atomic_fetch_add(bar, 1u, __ATOMIC_RELAXED, __HIP_MEMORY_SCOPE_AGENT);
            // prefetch next emb fragments into regs; overlaps barrier round-trip
            {
                const float* ep = emb + (long)tok_nxt * EMB + eoff;
                float4 a0 = *(const float4*)(ep);
                float4 a1 = *(const float4*)(ep + 4);
                float4 b0 = *(const float4*)(ep + 256);
                float4 b1 = *(const float4*)(ep + 260);
                fe0 = pack8(a0, a1);
                fe1 = pack8(b0, b1);
            }
            if (tid == 0) {
                unsigned tgt = (unsigned)(t + 1) * 16u;
                while (__hip_atomic_load(bar, __ATOMIC_RELAXED, __HIP_MEMORY_SCOPE_AGENT) < tgt)
                    __builtin_amdgcn_s_sleep(1);
            }
            __syncthreads();
        }
    }
}

// ---------------- final FC: logits = h @ Wfc + bfc, full fp32 ----------------
__global__ __launch_bounds__(256) void mgu_fc(const float* __restrict__ h,
                                              const float* __restrict__ Wfc,
                                              const float* __restrict__ bfc,
                                              float* __restrict__ out) {
    __shared__ float hs[BATCH][65];
    const int tid = threadIdx.x;
    const int n0  = blockIdx.x * 8;
    const int b   = tid & 127;
    const int nn  = tid >> 7;
    const int nc  = n0 + nn * 4;
    float acc0 = 0.f, acc1 = 0.f, acc2 = 0.f, acc3 = 0.f;

    for (int k0 = 0; k0 < HID; k0 += 64) {
        __syncthreads();
#pragma unroll
        for (int jj = 0; jj < 8; ++jj) {
            int idx = tid + jj * 256;
            int bb  = idx >> 4;
            int kk  = (idx & 15) << 2;
            const float4 v = *(const float4*)(h + bb * HID + k0 + kk);
            hs[bb][kk] = v.x; hs[bb][kk + 1] = v.y; hs[bb][kk + 2] = v.z; hs[bb][kk + 3] = v.w;
        }
        __syncthreads();
#pragma unroll 8
        for (int k = 0; k < 64; ++k) {
            float hv = hs[b][k];
            const float4 wv = *(const float4*)(Wfc + (long)(k0 + k) * NCLS + nc);
            acc0 += hv * wv.x; acc1 += hv * wv.y; acc2 += hv * wv.z; acc3 += hv * wv.w;
        }
    }
    float* op = out + b * NCLS + nc;
    op[0] = acc0 + bfc[nc + 0];
    op[1] = acc1 + bfc[nc + 1];
    op[2] = acc2 + bfc[nc + 2];
    op[3] = acc3 + bfc[nc + 3];
}

extern "C" void kernel_launch(void* const* d_in, const int* in_sizes, int n_in,
                              void* d_out, int out_size, void* d_ws, size_t ws_size,
                              hipStream_t stream) {
    const int*   x   = (const int*)  d_in[0];
    const float* emb = (const float*)d_in[1];
    const float* Wz  = (const float*)d_in[2];
    const float* bz  = (const float*)d_in[3];
    const float* Wh  = (const float*)d_in[4];
    const float* bh  = (const float*)d_in[5];
    const float* Wfc = (const float*)d_in[6];
    const float* bfc = (const float*)d_in[7];
    float* out = (float*)d_out;

    char* ws = (char*)d_ws;
    short*    ch0  = (short*)   (ws + OFF_CH0);
    short*    cl0  = (short*)   (ws + OFF_CL0);
    unsigned* bars = (unsigned*)(ws + OFF_BAR);
    short*    ch1  = (short*)   (ws + OFF_CH1);
    short*    cl1  = (short*)   (ws + OFF_CL1);
    float*    h    = (float*)   (ws + OFF_H);

    mgu_init<<<129, 256, 0, stream>>>((int4*)ws);   // zero ch0/cl0/bars

    mgu_scan<<<NBLK, TPB, 0, stream>>>(x, emb, Wz, bz, Wh, bh,
                                       ch0, cl0, ch1, cl1, bars, h);

    mgu_fc<<<125, 256, 0, stream>>>(h, Wfc, bfc, out);
}